// Round 1
// baseline (111.386 us; speedup 1.0000x reference)
//
#include <hip/hip_runtime.h>

#define N 2048
#define IN_DIM 32
#define L 64
#define LDSS 68  // padded LDS row stride (floats): 68%32=4 -> conflict-free pattern, 16B-aligned rows

// ---------------------------------------------------------------------------
// Kernel A: per-node precompute.
//   z    = lrelu(x @ W_ne + b_ne)            [N,64]
//   zi   = z @ W_e1a                          [N,64]
//   zjb  = z @ W_e1b + b_e1                   [N,64]
//   A[i] = 0.505 * sum_l w2[l]*zi[i,l]
//   B[j] = 0.505 * sum_l w2[l]*zjb[j,l] + b_e2
//   w2p  = 0.495 * w2
// One 64-thread block (one wave) per row; thread l owns column l.
// ---------------------------------------------------------------------------
__global__ __launch_bounds__(64) void precompute_kernel(
    const float* __restrict__ x,
    const float* __restrict__ W_ne,
    const float* __restrict__ b_ne,
    const float* __restrict__ W_e1a,
    const float* __restrict__ W_e1b,
    const float* __restrict__ b_e1,
    const float* __restrict__ w_e2,
    const float* __restrict__ b_e2,
    float* __restrict__ zi_g,
    float* __restrict__ zjb_g,
    float* __restrict__ A_g,
    float* __restrict__ B_g,
    float* __restrict__ w2p_g)
{
    const int i = blockIdx.x;
    const int l = threadIdx.x;
    __shared__ float zrow[L];

    float acc = b_ne[l];
    #pragma unroll
    for (int k = 0; k < IN_DIM; ++k)
        acc = fmaf(x[i * IN_DIM + k], W_ne[k * L + l], acc);   // x row is wave-uniform -> s_load
    float z = fmaxf(acc, 0.01f * acc);
    zrow[l] = z;
    __syncthreads();

    float vi = 0.0f, vj = b_e1[l];
    #pragma unroll 8
    for (int m = 0; m < L; ++m) {
        float zm = zrow[m];                                    // LDS broadcast
        vi = fmaf(zm, W_e1a[m * L + l], vi);
        vj = fmaf(zm, W_e1b[m * L + l], vj);
    }
    zi_g[i * L + l]  = vi;
    zjb_g[i * L + l] = vj;

    float w = w_e2[l];
    float ta = w * vi, tb = w * vj;
    #pragma unroll
    for (int off = 32; off > 0; off >>= 1) {
        ta += __shfl_xor(ta, off);
        tb += __shfl_xor(tb, off);
    }
    if (l == 0) {
        A_g[i] = 0.505f * ta;
        B_g[i] = 0.505f * tb + b_e2[0];
    }
    if (i == 0) w2p_g[l] = 0.495f * w;
}

// ---------------------------------------------------------------------------
// Kernel B: the N x N edge map.
//   logit[i,j] = A[i] + B[j] + sum_l w2p[l] * |zi[i,l] + zjb[j,l]|
//   out[i,j]   = (sigmoid(logit) + 1e-8) * exp(gumbel[i,j])
// 64x64 output tile per 256-thread block, 4x4 micro-tile per thread with
// strided element mapping (i = ty+16*ri, j = tx+16*rj) so zjb LDS reads are
// only 2-way bank-aliased (free) and zi reads are 16-lane broadcasts.
// ---------------------------------------------------------------------------
__global__ __launch_bounds__(256) void edge_kernel(
    const float* __restrict__ zi_g,
    const float* __restrict__ zjb_g,
    const float* __restrict__ A_g,
    const float* __restrict__ B_g,
    const float* __restrict__ w2p_g,
    const float* __restrict__ gumbel,
    float* __restrict__ out)
{
    __shared__ float zi_s[64 * LDSS];
    __shared__ float zj_s[64 * LDSS];

    const int jb = blockIdx.x * 64;
    const int ib = blockIdx.y * 64;
    const int t  = threadIdx.x;
    const int tx = t & 15;
    const int ty = t >> 4;

    // Stage 64x64 fp32 tiles of zi (rows = i) and zjb (rows = j) into LDS.
    #pragma unroll
    for (int rep = 0; rep < 4; ++rep) {
        int idx  = rep * 256 + t;
        int row  = idx >> 4;
        int col4 = (idx & 15) * 4;
        *(float4*)&zi_s[row * LDSS + col4] = *(const float4*)&zi_g[(ib + row) * L + col4];
        *(float4*)&zj_s[row * LDSS + col4] = *(const float4*)&zjb_g[(jb + row) * L + col4];
    }
    __syncthreads();

    float acc[4][4];
    #pragma unroll
    for (int a = 0; a < 4; ++a)
        #pragma unroll
        for (int b = 0; b < 4; ++b) acc[a][b] = 0.0f;

    const float4* __restrict__ w4 = (const float4*)w2p_g;  // wave-uniform -> s_load_dwordx4

    #pragma unroll
    for (int lq = 0; lq < 16; ++lq) {
        float4 w = w4[lq];
        float4 ai[4], bj[4];
        #pragma unroll
        for (int r = 0; r < 4; ++r) {
            ai[r] = *(const float4*)&zi_s[(ty + 16 * r) * LDSS + lq * 4];
            bj[r] = *(const float4*)&zj_s[(tx + 16 * r) * LDSS + lq * 4];
        }
        #pragma unroll
        for (int ri = 0; ri < 4; ++ri)
            #pragma unroll
            for (int rj = 0; rj < 4; ++rj) {
                float sx = ai[ri].x + bj[rj].x;
                float sy = ai[ri].y + bj[rj].y;
                float sz = ai[ri].z + bj[rj].z;
                float sw = ai[ri].w + bj[rj].w;
                float a0 = acc[ri][rj];
                a0 = fmaf(w.x, fabsf(sx), a0);   // abs folds into VOP3 input modifier
                a0 = fmaf(w.y, fabsf(sy), a0);
                a0 = fmaf(w.z, fabsf(sz), a0);
                a0 = fmaf(w.w, fabsf(sw), a0);
                acc[ri][rj] = a0;
            }
    }

    float Ai[4], Bj[4];
    #pragma unroll
    for (int r = 0; r < 4; ++r) {
        Ai[r] = A_g[ib + ty + 16 * r];
        Bj[r] = B_g[jb + tx + 16 * r];
    }

    #pragma unroll
    for (int ri = 0; ri < 4; ++ri) {
        int gi = ib + ty + 16 * ri;
        #pragma unroll
        for (int rj = 0; rj < 4; ++rj) {
            int gj = jb + tx + 16 * rj;
            float logit = Ai[ri] + Bj[rj] + acc[ri][rj];
            float p = 1.0f / (1.0f + __expf(-logit));
            float g = gumbel[(size_t)gi * N + gj];
            // exp(log(p+1e-8)+g) == (p+1e-8)*exp(g)
            out[(size_t)gi * N + gj] = (p + 1e-8f) * __expf(g);
        }
    }
}

extern "C" void kernel_launch(void* const* d_in, const int* in_sizes, int n_in,
                              void* d_out, int out_size, void* d_ws, size_t ws_size,
                              hipStream_t stream) {
    const float* x      = (const float*)d_in[0];
    // d_in[1] = in_adj — unused by the reference computation
    const float* gumbel = (const float*)d_in[2];
    const float* W_ne   = (const float*)d_in[3];
    const float* b_ne   = (const float*)d_in[4];
    const float* W_e1a  = (const float*)d_in[5];
    const float* W_e1b  = (const float*)d_in[6];
    const float* b_e1   = (const float*)d_in[7];
    const float* w_e2   = (const float*)d_in[8];
    const float* b_e2   = (const float*)d_in[9];
    float* out = (float*)d_out;

    char* ws = (char*)d_ws;
    float* zi_g  = (float*)(ws);                          // 512 KB
    float* zjb_g = (float*)(ws + 512 * 1024);             // 512 KB
    float* A_g   = (float*)(ws + 1024 * 1024);            // 8 KB
    float* B_g   = (float*)(ws + 1024 * 1024 + 8 * 1024); // 8 KB
    float* w2p_g = (float*)(ws + 1024 * 1024 + 16 * 1024);// 256 B

    precompute_kernel<<<N, 64, 0, stream>>>(x, W_ne, b_ne, W_e1a, W_e1b, b_e1,
                                            w_e2, b_e2, zi_g, zjb_g, A_g, B_g, w2p_g);
    edge_kernel<<<dim3(N / 64, N / 64), 256, 0, stream>>>(zi_g, zjb_g, A_g, B_g,
                                                          w2p_g, gumbel, out);
}